// Round 6
// baseline (233.362 us; speedup 1.0000x reference)
//
#include <hip/hip_runtime.h>
#include <cstdint>
#include <cstddef>

// B=2, T=4096, C=1024, H=4, G=1, hd=256, window=512, rope base 1e6, eps 1e-6.
#define T_SEQ 4096
#define NB    2
#define CDIM  1024
#define HD    256
#define NH    4

typedef __attribute__((ext_vector_type(8))) __bf16 bf16x8;
typedef __attribute__((ext_vector_type(4))) __bf16 bf16x4;
typedef __attribute__((ext_vector_type(4))) float  floatx4;
typedef __attribute__((ext_vector_type(16))) float f32x16;

__device__ __forceinline__ floatx4 mfma16(bf16x8 a, bf16x8 b, floatx4 c) {
  return __builtin_amdgcn_mfma_f32_16x16x32_bf16(a, b, c, 0, 0, 0);
}
__device__ __forceinline__ f32x16 mfma32(bf16x8 a, bf16x8 b, f32x16 c) {
  return __builtin_amdgcn_mfma_f32_32x32x16_bf16(a, b, c, 0, 0, 0);
}

// async global->LDS, 16B/lane. LDS dest is wave-uniform base + lane*16 (no
// scatter) -- bank-deconflict swizzles are applied to the GLOBAL source
// address (XOR of the 16B-chunk index, stays inside one row's span).
__device__ __forceinline__ void gl2lds16(const void* g, void* l) {
  __builtin_amdgcn_global_load_lds(
      (__attribute__((address_space(1))) void*)g,
      (__attribute__((address_space(3))) void*)l, 16, 0, 0);
}

// ------------------------------------------- fp32 -> bf16, all 5 inputs fused
__global__ __launch_bounds__(256) void cvt_all(const float* __restrict__ x,
                                               const float* __restrict__ wq,
                                               const float* __restrict__ wk,
                                               const float* __restrict__ wv,
                                               const float* __restrict__ wo,
                                               __bf16* __restrict__ xb,
                                               __bf16* __restrict__ wb,
                                               __bf16* __restrict__ wob) {
  int i = blockIdx.x * 256 + threadIdx.x;   // float4 index, [0, 2752512)
  const float* src;
  __bf16* dst;
  int off;
  if (i < 2097152)      { src = x;  dst = xb;            off = i; }
  else if (i < 2359296) { src = wq; dst = wb;            off = i - 2097152; }
  else if (i < 2424832) { src = wk; dst = wb + 1048576;  off = i - 2359296; }
  else if (i < 2490368) { src = wv; dst = wb + 1310720;  off = i - 2424832; }
  else                  { src = wo; dst = wob;           off = i - 2490368; }
  float4 v = ((const float4*)src)[off];
  bf16x4 o;
  o[0] = (__bf16)v.x; o[1] = (__bf16)v.y; o[2] = (__bf16)v.z; o[3] = (__bf16)v.w;
  *(bf16x4*)&dst[(size_t)off * 4] = o;
}

// ------------------------------------------------- C(M,N) = A(M,K) @ B(N,K)^T
// m97 structure + XOR-swizzled LDS (R6-proven). Both A and B staged via
// global_load_lds (coalesced), 128x128 tile, BK=64, 2 barriers/iter,
// 32 KB LDS -> 3 blocks/CU. M,N multiples of 128; K multiple of 64.
template <typename OutT>
__global__ __launch_bounds__(256) void gemm_bt(const __bf16* __restrict__ A,
                                               const __bf16* __restrict__ B,
                                               OutT* __restrict__ C,
                                               int M, int N, int K) {
  __shared__ __bf16 As[128 * 64];
  __shared__ __bf16 Bs[128 * 64];
  const int tid  = threadIdx.x;
  const int lane = tid & 63;
  const int wave = tid >> 6;
  const int wm = wave >> 1, wn = wave & 1;
  const int lrow = lane & 15, quad = lane >> 4;
  const int bm = blockIdx.y, bn = blockIdx.x;

  const __bf16* gA = A + (size_t)(bm * 128) * K;
  const __bf16* gB = B + (size_t)(bn * 128) * K;
  const int arow = tid >> 3;
  const int acol = ((tid & 7) ^ ((tid >> 3) & 7)) * 8;
  const int l7 = lrow & 7;

  floatx4 acc[4][4] = {};

  for (int kt = 0; kt < K; kt += 64) {
#pragma unroll
    for (int i = 0; i < 4; ++i)
      gl2lds16(gA + (size_t)(i * 32 + arow) * K + kt + acol, &As[i * 2048 + tid * 8]);
#pragma unroll
    for (int i = 0; i < 4; ++i)
      gl2lds16(gB + (size_t)(i * 32 + arow) * K + kt + acol, &Bs[i * 2048 + tid * 8]);
    __syncthreads();
#pragma unroll
    for (int kk = 0; kk < 2; ++kk) {
      bf16x8 af[4], bfr[4];
#pragma unroll
      for (int mi = 0; mi < 4; ++mi)
        af[mi] = *(const bf16x8*)&As[(wm * 64 + mi * 16 + lrow) * 64 +
                                     ((kk * 4 + quad) ^ l7) * 8];
#pragma unroll
      for (int ni = 0; ni < 4; ++ni)
        bfr[ni] = *(const bf16x8*)&Bs[(wn * 64 + ni * 16 + lrow) * 64 +
                                      ((kk * 4 + quad) ^ l7) * 8];
#pragma unroll
      for (int mi = 0; mi < 4; ++mi)
#pragma unroll
        for (int ni = 0; ni < 4; ++ni)
          acc[mi][ni] = mfma16(af[mi], bfr[ni], acc[mi][ni]);
    }
    __syncthreads();
  }

  const int row0 = bm * 128 + wm * 64;
  const int col0 = bn * 128 + wn * 64;
#pragma unroll
  for (int mi = 0; mi < 4; ++mi)
#pragma unroll
    for (int ni = 0; ni < 4; ++ni)
#pragma unroll
      for (int r = 0; r < 4; ++r) {
        int row = row0 + mi * 16 + quad * 4 + r;   // C/D: row = quad*4 + reg
        int col = col0 + ni * 16 + lrow;           //      col = lane&15
        C[(size_t)row * N + col] = (OutT)acc[mi][ni][r];
      }
}

// ------------------------------------------------ RMSNorm + RoPE (+ V transpose)
__global__ __launch_bounds__(256) void rmsrope(const __bf16* __restrict__ qkv,
                                               const float* __restrict__ qg,
                                               const float* __restrict__ kg,
                                               __bf16* __restrict__ qr,
                                               __bf16* __restrict__ kr,
                                               __bf16* __restrict__ vt) {
  __shared__ __bf16 Ls[64 * 256];
  if (blockIdx.x >= 5120) {
    const int vb = blockIdx.x - 5120;      // 0..127
    const int b = vb >> 6, tt = vb & 63;
    const int tid = threadIdx.x;
    const __bf16* src = qkv + ((size_t)(b * 4096 + tt * 64)) * 1536 + 1280;
#pragma unroll
    for (int i = 0; i < 8; ++i)
      gl2lds16(src + (size_t)(i * 8 + (tid >> 5)) * 1536 + (tid & 31) * 8,
               &Ls[i * 2048 + tid * 8]);
    __syncthreads();
    __bf16 buf[64];
#pragma unroll
    for (int i = 0; i < 64; ++i) buf[i] = Ls[i * 256 + tid];
    __bf16* dst = vt + ((size_t)(b * 256 + tid)) * T_SEQ + tt * 64;
#pragma unroll
    for (int i = 0; i < 8; ++i)
      *(bf16x8*)&dst[i * 8] = *(const bf16x8*)&buf[i * 8];
    return;
  }

  const int inst = blockIdx.x * 4 + (threadIdx.x >> 6);
  const int lane = threadIdx.x & 63;
  const int rp = inst / 5, which = inst - rp * 5;     // rp in [0, 4096)
  const int row = rp * 2 + (lane >> 5);               // row in [0, 8192)
  const int hl = lane & 31;
  const int b = row >> 12, t = row & 4095;

  const int srcoff = (which < 4) ? which * 256 : 1024;
  const __bf16* src = qkv + (size_t)row * 1536 + srcoff;
  bf16x8 xv = *(const bf16x8*)&src[hl * 8];

  float xf[8];
  float ss = 0.f;
#pragma unroll
  for (int j = 0; j < 8; ++j) { xf[j] = (float)xv[j]; ss += xf[j] * xf[j]; }
#pragma unroll
  for (int off = 16; off >= 1; off >>= 1) ss += __shfl_xor(ss, off);
  const float rms = rsqrtf(ss * (1.0f / 256.0f) + 1e-6f);

  const float* g = (which < 4) ? qg : kg;
  const float4 gv0 = *(const float4*)&g[hl * 8];
  const float4 gv1 = *(const float4*)&g[hl * 8 + 4];
  float y[8];
  y[0] = xf[0] * rms * gv0.x; y[1] = xf[1] * rms * gv0.y;
  y[2] = xf[2] * rms * gv0.z; y[3] = xf[3] * rms * gv0.w;
  y[4] = xf[4] * rms * gv1.x; y[5] = xf[5] * rms * gv1.y;
  y[6] = xf[6] * rms * gv1.z; y[7] = xf[7] * rms * gv1.w;

  const float c_log2 = -19.931568569324174f / 128.0f;  // -log2(1e6)/128
  bf16x8 ov;
#pragma unroll
  for (int j = 0; j < 4; ++j) {
    const int p = hl * 4 + j;
    const float a = (float)t * exp2f((float)p * c_log2);
    const float sn = __sinf(a), cs = __cosf(a);
    ov[2 * j]     = (__bf16)(y[2 * j] * cs - y[2 * j + 1] * sn);
    ov[2 * j + 1] = (__bf16)(y[2 * j] * sn + y[2 * j + 1] * cs);
  }

  __bf16* dst = (which < 4)
      ? qr + ((size_t)((b * NH + which) * T_SEQ) + t) * 256
      : kr + ((size_t)(b * T_SEQ) + t) * 256;
  *(bf16x8*)&dst[hl * 8] = ov;
}

// --------------------------------------------------- flash attention, window=512
// R12: R11's 32x32/in-reg-softmax structure + the occupancy fix. R5 counters:
// Occ 9.3% = 1 wave/SIMD (4 waves, 1 block/CU) -> pure latency stall. Now 8
// waves (512 thr), same 256-block grid -> 2 waves/SIMD. Wave (qw=w&3, kw=w>>2):
// query-32 group x KEY-HALF-32 of each 64-key window. Fixed-max softmax makes
// o/l pure sums over keys, so the key split combines exactly by one post-loop
// LDS reduction (kw=1 dumps o+lm into the retired K/V buffers + 16KB, kw=0
// adds + stores; 2 uniform barriers). Per wave/window: 16 QK MFMA (d-steps),
// 2 lm, 16 PV; 8 gl2lds/thread staging. K swizzle upgraded to ^(row&31)
// (32 chunks/row) -> QK LDS reads conflict-free. V swizzle ^(row&7) kept
// (8 chunks/row, structural). VGPR ~228 -> launch_bounds(512,2) holds.
// XCD map: 32 consecutive bids = one (b,h) -> 4 MB K+V per XCD L2.
__global__ __launch_bounds__(512, 2) void attn(const __bf16* __restrict__ qr,
                                               const __bf16* __restrict__ kr,
                                               const __bf16* __restrict__ vt,
                                               __bf16* __restrict__ ao) {
  __shared__ __bf16 Ks[2][64 * 256];   // [key][d]   2 x 32 KB
  __shared__ __bf16 Vs[2][256 * 64];   // [d][key]   2 x 32 KB
  __shared__ float  Lx[4][1024];       // lm reduction, 16 KB

  const int bid = ((blockIdx.x & 7) << 5) | (blockIdx.x >> 3);
  const int qi = bid & 31, h = (bid >> 5) & 3, b = bid >> 7;
  const int tid = threadIdx.x, w = tid >> 6, lane = tid & 63;
  const int qw = w & 3, kw = w >> 2;
  const int l31 = lane & 31, hi = lane >> 5;

  const __bf16* Q = qr + (size_t)((b * NH + h) * T_SEQ) * 256;
  const __bf16* K = kr + (size_t)(b * T_SEQ) * 256;
  const __bf16* V = vt + (size_t)(b * 256) * T_SEQ;

  const int qbase = qi * 128;
  const int qg = qbase + qw * 32 + l31;         // this lane's query (QK col)
  const int wt0 = (qi >= 4) ? 2 * qi - 8 : 0;
  const int wt1 = 2 * qi + 1;

  // Q fragments (B-operand, 16 d-steps): qf[s] = Q[qg][s*16 + hi*8 .. +7]
  bf16x8 qf[16];
#pragma unroll
  for (int s = 0; s < 16; ++s)
    qf[s] = *(const bf16x8*)&Q[(size_t)qg * 256 + s * 16 + hi * 8];

  bf16x8 onesv;
#pragma unroll
  for (int j = 0; j < 8; ++j) onesv[j] = (__bf16)1.0f;

  f32x16 o[8] = {};
  f32x16 lm = {};

  const float C1 = 0.09016844005556021f;   // log2(e)/16
  const float C2 = 23.083120654223415f;    // 16*log2(e)

  // ---- staging: 512 threads, 8 gl2lds each (K: 4 rounds, V: 4 rounds).
  // K global chunk pre-swizzled ^(row&31); V ^(row&7). LDS dest linear tid*16B.
#define STAGE_KV(WT)                                                          \
  {                                                                           \
    const int wt_ = (WT);                                                     \
    __bf16* kd = Ks[wt_ & 1];                                                 \
    __bf16* vd = Vs[wt_ & 1];                                                 \
    _Pragma("unroll")                                                         \
    for (int i = 0; i < 4; ++i) {                                             \
      const int row = i * 16 + (tid >> 5);                                    \
      const int g = (tid & 31) ^ (row & 31);                                  \
      gl2lds16(K + (size_t)(wt_ * 64 + row) * 256 + g * 8,                    \
               kd + i * 4096 + tid * 8);                                      \
    }                                                                         \
    _Pragma("unroll")                                                         \
    for (int i = 0; i < 4; ++i) {                                             \
      const int row = i * 64 + (tid >> 3);                                    \
      const int g = (tid & 7) ^ (row & 7);                                    \
      gl2lds16(V + (size_t)row * T_SEQ + wt_ * 64 + g * 8,                    \
               vd + i * 4096 + tid * 8);                                      \
    }                                                                         \
  }

  // prologue: stage first tile, drain, barrier
  STAGE_KV(wt0);
  asm volatile("s_waitcnt vmcnt(0)\n\ts_barrier" ::: "memory");

  for (int wt = wt0; wt <= wt1; ++wt) {
    if (wt < wt1) STAGE_KV(wt + 1);    // overlaps compute; drained at bottom

    const __bf16* Kb = Ks[wt & 1];
    const __bf16* Vb = Vs[wt & 1];

    // ---- QK^T: this wave's 32 keys (kw half) x its 32 queries, 16 d-steps
    f32x16 s = {};
    __builtin_amdgcn_s_setprio(1);
#pragma unroll
    for (int st = 0; st < 16; ++st) {
      bf16x8 kf = *(const bf16x8*)&Kb[(kw * 32 + l31) * 256 +
                                      (((st * 2 + hi) ^ l31) * 8)];
      s = mfma32(kf, qf[st], s);
    }
    __builtin_amdgcn_s_setprio(0);

    // ---- mask + exp (fixed-max): p = exp2(s*C1 - C2)
    const bool full = (wt <= 2 * qi - 1) && (wt >= 2 * qi - 6);
    float p[16];
#pragma unroll
    for (int r = 0; r < 16; ++r) {
      const int crow = (r & 3) + 8 * (r >> 2) + 4 * hi;
      float v = s[r];
      if (!full) {
        const int k = wt * 64 + kw * 32 + crow;
        v = ((k <= qg) && (k + 512 >= qg)) ? v : -1e30f;
      }
      p[r] = exp2f(v * C1 - C2);
    }

    // ---- P -> PA fragments, in-register (cvt_pk + half-wave swap; R11-verified)
    bf16x8 pa[2];
#pragma unroll
    for (int kh = 0; kh < 2; ++kh) {
      unsigned X0, X1, Y0, Y1;
      asm("v_cvt_pk_bf16_f32 %0, %1, %2" : "=v"(X0) : "v"(p[kh * 8 + 0]), "v"(p[kh * 8 + 1]));
      asm("v_cvt_pk_bf16_f32 %0, %1, %2" : "=v"(X1) : "v"(p[kh * 8 + 2]), "v"(p[kh * 8 + 3]));
      asm("v_cvt_pk_bf16_f32 %0, %1, %2" : "=v"(Y0) : "v"(p[kh * 8 + 4]), "v"(p[kh * 8 + 5]));
      asm("v_cvt_pk_bf16_f32 %0, %1, %2" : "=v"(Y1) : "v"(p[kh * 8 + 6]), "v"(p[kh * 8 + 7]));
      const unsigned pX0 = __shfl_xor(X0, 32), pX1 = __shfl_xor(X1, 32);
      const unsigned pY0 = __shfl_xor(Y0, 32), pY1 = __shfl_xor(Y1, 32);
      uint4 wv;
      wv.x = hi ? pY0 : X0;
      wv.y = hi ? pY1 : X1;
      wv.z = hi ? Y0 : pX0;
      wv.w = hi ? Y1 : pX1;
      pa[kh] = __builtin_bit_cast(bf16x8, wv);
    }

    // ---- l accumulation (D layout == o) + PV over this wave's key half
    __builtin_amdgcn_s_setprio(1);
    lm = mfma32(pa[0], onesv, lm);
    lm = mfma32(pa[1], onesv, lm);
#pragma unroll
    for (int n = 0; n < 8; ++n) {
      const int vrow = (n * 32 + l31) * 64;
#pragma unroll
      for (int kh = 0; kh < 2; ++kh) {
        bf16x8 vf = *(const bf16x8*)&Vb[vrow +
                                        (((kw * 4 + kh * 2 + hi) ^ (l31 & 7)) * 8)];
        o[n] = mfma32(pa[kh], vf, o[n]);
      }
    }
    __builtin_amdgcn_s_setprio(0);

    if (wt < wt1)
      asm volatile("s_waitcnt vmcnt(0) lgkmcnt(0)\n\ts_barrier" ::: "memory");
  }
#undef STAGE_KV

  // ---- key-half combine: kw=1 dumps o+lm into retired LDS, kw=0 adds.
  // E1: every wave's last-window ds_reads done before buffers are reused.
  asm volatile("s_waitcnt lgkmcnt(0)\n\ts_barrier" ::: "memory");

  float* red  = (qw < 2) ? ((float*)Ks + qw * 8192) : ((float*)Vs + (qw - 2) * 8192);
  float* lred = Lx[qw];

  if (kw == 1) {
#pragma unroll
    for (int n = 0; n < 8; ++n)
#pragma unroll
      for (int r = 0; r < 16; ++r)
        red[(n * 16 + r) * 64 + lane] = o[n][r];
#pragma unroll
    for (int r = 0; r < 16; ++r)
      lred[r * 64 + lane] = lm[r];
  }
  // E2: partials visible
  asm volatile("s_waitcnt lgkmcnt(0)\n\ts_barrier" ::: "memory");

  if (kw == 0) {
#pragma unroll
    for (int r = 0; r < 16; ++r) lm[r] += lred[r * 64 + lane];
#pragma unroll
    for (int n = 0; n < 8; ++n)
#pragma unroll
      for (int r = 0; r < 16; ++r)
        o[n][r] += red[(n * 16 + r) * 64 + lane];

    // epilogue: O/l -> ao in (B,T,H*hd) layout. rows q = crow(r,hi), cols d.
#pragma unroll
    for (int r = 0; r < 16; ++r) {
      const float rl = 1.0f / lm[r];
      const int qrow = qbase + qw * 32 + (r & 3) + 8 * (r >> 2) + 4 * hi;
#pragma unroll
      for (int n = 0; n < 8; ++n)
        ao[((size_t)(b * T_SEQ + qrow)) * CDIM + h * 256 + n * 32 + l31] =
            (__bf16)(o[n][r] * rl);
    }
  }
}

// -----------------------------------------------------------------------------
extern "C" void kernel_launch(void* const* d_in, const int* in_sizes, int n_in,
                              void* d_out, int out_size, void* d_ws, size_t ws_size,
                              hipStream_t stream) {
  const float* x  = (const float*)d_in[0];
  const float* Wq = (const float*)d_in[1];
  const float* Wk = (const float*)d_in[2];
  const float* Wv = (const float*)d_in[3];
  const float* Wo = (const float*)d_in[4];
  const float* qg = (const float*)d_in[5];
  const float* kg = (const float*)d_in[6];
  float* out = (float*)d_out;

  const size_t M = (size_t)NB * T_SEQ;  // 8192
  char* ws = (char*)d_ws;
  __bf16* xb  = (__bf16*)ws; ws += M * CDIM * 2;
  __bf16* wb  = (__bf16*)ws; ws += (size_t)1536 * CDIM * 2;
  __bf16* wob = (__bf16*)ws; ws += (size_t)CDIM * CDIM * 2;
  __bf16* qkv = (__bf16*)ws; ws += M * 1536 * 2;
  __bf16* qr  = (__bf16*)ws; ws += M * CDIM * 2;
  __bf16* kr  = (__bf16*)ws; ws += M * HD * 2;
  __bf16* vt  = (__bf16*)ws; ws += M * HD * 2;
  __bf16* ao  = (__bf16*)ws;

  // all fp32->bf16 conversions in one launch
  cvt_all<<<10752, 256, 0, stream>>>(x, Wq, Wk, Wv, Wo, xb, wb, wob);

  // QKV projection: (8192 x 1536) = xb @ [Wq;Wk;Wv]^T
  gemm_bt<__bf16><<<dim3(12, 64), 256, 0, stream>>>(xb, wb, qkv, 8192, 1536, 1024);

  // per-head RMSNorm + RoPE on Q,K; V transpose via LDS tiles
  rmsrope<<<5248, 256, 0, stream>>>(qkv, qg, kg, qr, kr, vt);

  // sliding-window flash attention: 128-query blocks, 64-key tiles,
  // 32x32 MFMA + in-register softmax, 8 waves (key-split), 2 waves/SIMD
  attn<<<NB * NH * (T_SEQ / 128), 512, 0, stream>>>(qr, kr, vt, ao);

  // output projection to fp32 d_out
  gemm_bt<float><<<dim3(8, 64), 256, 0, stream>>>(ao, wob, out, 8192, 1024, 1024);
}

// Round 8
// 218.541 us; speedup vs baseline: 1.0678x; 1.0678x over previous
//
#include <hip/hip_runtime.h>
#include <cstdint>
#include <cstddef>

// B=2, T=4096, C=1024, H=4, G=1, hd=256, window=512, rope base 1e6, eps 1e-6.
#define T_SEQ 4096
#define NB    2
#define CDIM  1024
#define HD    256
#define NH    4

typedef __attribute__((ext_vector_type(8))) __bf16 bf16x8;
typedef __attribute__((ext_vector_type(4))) __bf16 bf16x4;
typedef __attribute__((ext_vector_type(4))) float  floatx4;

__device__ __forceinline__ floatx4 mfma16(bf16x8 a, bf16x8 b, floatx4 c) {
  return __builtin_amdgcn_mfma_f32_16x16x32_bf16(a, b, c, 0, 0, 0);
}

// async global->LDS, 16B/lane. LDS dest is wave-uniform base + lane*16 (no
// scatter) -- bank-deconflict swizzles are applied to the GLOBAL source
// address (XOR of the 16B-chunk index, stays inside one row's span).
// CROSS-WAVE VISIBILITY RULE (R14, learned from the R13 failure): another
// wave's gl2lds write is visible ONLY after that wave drains it with a
// s_waitcnt vmcnt(N) placed BEFORE the shared s_barrier. A wave waiting on
// its OWN vmcnt after the barrier proves nothing about siblings' stages.
__device__ __forceinline__ void gl2lds16(const void* g, void* l) {
  __builtin_amdgcn_global_load_lds(
      (__attribute__((address_space(1))) void*)g,
      (__attribute__((address_space(3))) void*)l, 16, 0, 0);
}

// ------------------------------------------- fp32 -> bf16, all 5 inputs fused
__global__ __launch_bounds__(256) void cvt_all(const float* __restrict__ x,
                                               const float* __restrict__ wq,
                                               const float* __restrict__ wk,
                                               const float* __restrict__ wv,
                                               const float* __restrict__ wo,
                                               __bf16* __restrict__ xb,
                                               __bf16* __restrict__ wb,
                                               __bf16* __restrict__ wob) {
  int i = blockIdx.x * 256 + threadIdx.x;   // float4 index, [0, 2752512)
  const float* src;
  __bf16* dst;
  int off;
  if (i < 2097152)      { src = x;  dst = xb;            off = i; }
  else if (i < 2359296) { src = wq; dst = wb;            off = i - 2097152; }
  else if (i < 2424832) { src = wk; dst = wb + 1048576;  off = i - 2359296; }
  else if (i < 2490368) { src = wv; dst = wb + 1310720;  off = i - 2424832; }
  else                  { src = wo; dst = wob;           off = i - 2490368; }
  float4 v = ((const float4*)src)[off];
  bf16x4 o;
  o[0] = (__bf16)v.x; o[1] = (__bf16)v.y; o[2] = (__bf16)v.z; o[3] = (__bf16)v.w;
  *(bf16x4*)&dst[(size_t)off * 4] = o;
}

// ------------------------------------------------- C(M,N) = A(M,K) @ B(N,K)^T
// R14: REVERT to the proven 128x128 single-buffer m97 structure (passed rounds
// 0-5). Both A and B staged via global_load_lds (coalesced), BK=64, 2 barriers
// per iter (__syncthreads = full vmcnt+lgkm drain + barrier -> formally safe),
// 32 KB LDS -> 3 blocks/CU. M,N multiples of 128; K multiple of 64.
// The 256^2 multi-phase experiment returns next round as an isolated change.
template <typename OutT>
__global__ __launch_bounds__(256) void gemm_bt(const __bf16* __restrict__ A,
                                               const __bf16* __restrict__ B,
                                               OutT* __restrict__ C,
                                               int M, int N, int K) {
  __shared__ __bf16 As[128 * 64];
  __shared__ __bf16 Bs[128 * 64];
  const int tid  = threadIdx.x;
  const int lane = tid & 63;
  const int wave = tid >> 6;
  const int wm = wave >> 1, wn = wave & 1;
  const int lrow = lane & 15, quad = lane >> 4;
  const int bm = blockIdx.y, bn = blockIdx.x;

  const __bf16* gA = A + (size_t)(bm * 128) * K;
  const __bf16* gB = B + (size_t)(bn * 128) * K;
  const int arow = tid >> 3;
  const int acol = ((tid & 7) ^ ((tid >> 3) & 7)) * 8;
  const int l7 = lrow & 7;

  floatx4 acc[4][4] = {};

  for (int kt = 0; kt < K; kt += 64) {
#pragma unroll
    for (int i = 0; i < 4; ++i)
      gl2lds16(gA + (size_t)(i * 32 + arow) * K + kt + acol, &As[i * 2048 + tid * 8]);
#pragma unroll
    for (int i = 0; i < 4; ++i)
      gl2lds16(gB + (size_t)(i * 32 + arow) * K + kt + acol, &Bs[i * 2048 + tid * 8]);
    __syncthreads();
#pragma unroll
    for (int kk = 0; kk < 2; ++kk) {
      bf16x8 af[4], bfr[4];
#pragma unroll
      for (int mi = 0; mi < 4; ++mi)
        af[mi] = *(const bf16x8*)&As[(wm * 64 + mi * 16 + lrow) * 64 +
                                     ((kk * 4 + quad) ^ l7) * 8];
#pragma unroll
      for (int ni = 0; ni < 4; ++ni)
        bfr[ni] = *(const bf16x8*)&Bs[(wn * 64 + ni * 16 + lrow) * 64 +
                                      ((kk * 4 + quad) ^ l7) * 8];
#pragma unroll
      for (int mi = 0; mi < 4; ++mi)
#pragma unroll
        for (int ni = 0; ni < 4; ++ni)
          acc[mi][ni] = mfma16(af[mi], bfr[ni], acc[mi][ni]);
    }
    __syncthreads();
  }

  const int row0 = bm * 128 + wm * 64;
  const int col0 = bn * 128 + wn * 64;
#pragma unroll
  for (int mi = 0; mi < 4; ++mi)
#pragma unroll
    for (int ni = 0; ni < 4; ++ni)
#pragma unroll
      for (int r = 0; r < 4; ++r) {
        int row = row0 + mi * 16 + quad * 4 + r;   // C/D: row = quad*4 + reg
        int col = col0 + ni * 16 + lrow;           //      col = lane&15
        C[(size_t)row * N + col] = (OutT)acc[mi][ni][r];
      }
}

// ------------------------------------------------ RMSNorm + RoPE (+ V transpose)
__global__ __launch_bounds__(256) void rmsrope(const __bf16* __restrict__ qkv,
                                               const float* __restrict__ qg,
                                               const float* __restrict__ kg,
                                               __bf16* __restrict__ qr,
                                               __bf16* __restrict__ kr,
                                               __bf16* __restrict__ vt) {
  __shared__ __bf16 Ls[64 * 256];
  if (blockIdx.x >= 5120) {
    const int vb = blockIdx.x - 5120;      // 0..127
    const int b = vb >> 6, tt = vb & 63;
    const int tid = threadIdx.x;
    const __bf16* src = qkv + ((size_t)(b * 4096 + tt * 64)) * 1536 + 1280;
#pragma unroll
    for (int i = 0; i < 8; ++i)
      gl2lds16(src + (size_t)(i * 8 + (tid >> 5)) * 1536 + (tid & 31) * 8,
               &Ls[i * 2048 + tid * 8]);
    __syncthreads();
    __bf16 buf[64];
#pragma unroll
    for (int i = 0; i < 64; ++i) buf[i] = Ls[i * 256 + tid];
    __bf16* dst = vt + ((size_t)(b * 256 + tid)) * T_SEQ + tt * 64;
#pragma unroll
    for (int i = 0; i < 8; ++i)
      *(bf16x8*)&dst[i * 8] = *(const bf16x8*)&buf[i * 8];
    return;
  }

  const int inst = blockIdx.x * 4 + (threadIdx.x >> 6);
  const int lane = threadIdx.x & 63;
  const int rp = inst / 5, which = inst - rp * 5;     // rp in [0, 4096)
  const int row = rp * 2 + (lane >> 5);               // row in [0, 8192)
  const int hl = lane & 31;
  const int b = row >> 12, t = row & 4095;

  const int srcoff = (which < 4) ? which * 256 : 1024;
  const __bf16* src = qkv + (size_t)row * 1536 + srcoff;
  bf16x8 xv = *(const bf16x8*)&src[hl * 8];

  float xf[8];
  float ss = 0.f;
#pragma unroll
  for (int j = 0; j < 8; ++j) { xf[j] = (float)xv[j]; ss += xf[j] * xf[j]; }
#pragma unroll
  for (int off = 16; off >= 1; off >>= 1) ss += __shfl_xor(ss, off);
  const float rms = rsqrtf(ss * (1.0f / 256.0f) + 1e-6f);

  const float* g = (which < 4) ? qg : kg;
  const float4 gv0 = *(const float4*)&g[hl * 8];
  const float4 gv1 = *(const float4*)&g[hl * 8 + 4];
  float y[8];
  y[0] = xf[0] * rms * gv0.x; y[1] = xf[1] * rms * gv0.y;
  y[2] = xf[2] * rms * gv0.z; y[3] = xf[3] * rms * gv0.w;
  y[4] = xf[4] * rms * gv1.x; y[5] = xf[5] * rms * gv1.y;
  y[6] = xf[6] * rms * gv1.z; y[7] = xf[7] * rms * gv1.w;

  const float c_log2 = -19.931568569324174f / 128.0f;  // -log2(1e6)/128
  bf16x8 ov;
#pragma unroll
  for (int j = 0; j < 4; ++j) {
    const int p = hl * 4 + j;
    const float a = (float)t * exp2f((float)p * c_log2);
    const float sn = __sinf(a), cs = __cosf(a);
    ov[2 * j]     = (__bf16)(y[2 * j] * cs - y[2 * j + 1] * sn);
    ov[2 * j + 1] = (__bf16)(y[2 * j] * sn + y[2 * j + 1] * cs);
  }

  __bf16* dst = (which < 4)
      ? qr + ((size_t)((b * NH + which) * T_SEQ) + t) * 256
      : kr + ((size_t)(b * T_SEQ) + t) * 256;
  *(bf16x8*)&dst[hl * 8] = ov;
}

// --------------------------------------------------- flash attention, window=512
// R14: R10's producer/consumer structure with FORMALLY CORRECT sync.
// R13 failure root-cause: R10 waited own-vmcnt AFTER the barrier -> other
// waves' K/V stages (and first-window LDS init) not guaranteed visible.
// Fix: counted vmcnt BEFORE every shared barrier + 2-tile staging lead +
// 3-deep K/V buffers (mod-3 rotation) so the lead never writes a live buffer.
//   QK waves 0-3 (kb=w&1 key-16, qh=w>>1 query-32): prologue stages K(jt0),
//   K(jt0+1), waits vmcnt(4) [K(jt0) landed] before the prologue barrier.
//   Iter jt: stage K(jt+2) if any; read K(jt) (landed at previous barrier);
//   MFMA; exp; write P(jt); wait lgkm(0)+vmcnt(4|0) [drains K(jt+1)]; barrier.
//   PV waves 4-7 (d-64 slice): prologue stages V(jt0); barrier. Iter ii:
//   stage V(jt0+ii+1) if any; consume P/V(jt0+ii-1) (landed at prev barrier);
//   wait vmcnt(4|0) [drains V(jt0+ii)]; barrier (ii<NT).
// Live/in-flight sets disjoint mod 3 (verified); barrier counts match (1+NT
// per group); edges NT=2 and tails re-simulated. LDS 104 KB -> 1 block/CU,
// 8 waves (R2 vs R9: 8 vs 16 waves/CU measured neutral for this kernel).
// Fixed-max softmax (|score|<=16): p = exp2(s*log2e/16 - 16*log2e); l via
// ones-MFMA. Swizzles: K chunk^(row&7); V/P chunk^((row^(row>>2))&3).
// XCD map: each XCD = one (b,h) -> 4MB K+V in its L2.
__global__ __launch_bounds__(512, 2) void attn(const __bf16* __restrict__ qr,
                                               const __bf16* __restrict__ kr,
                                               const __bf16* __restrict__ vt,
                                               __bf16* __restrict__ ao) {
  __shared__ __bf16 Ks[3][32 * 256];   // [key][d]   (3 x 16 KB)
  __shared__ __bf16 Vs[3][256 * 32];   // [d][key]   (3 x 16 KB)
  __shared__ __bf16 Ps[2][64 * 32];    // [query][key] (2 x 4 KB)

  const int bid = ((blockIdx.x & 7) << 6) | (blockIdx.x >> 3);
  const int qi = bid & 63, h = (bid >> 6) & 3, b = bid >> 8;
  const int tid = threadIdx.x, wave = tid >> 6, lane = tid & 63;
  const int lrow = lane & 15, quad = lane >> 4;
  const int l7 = lrow & 7;

  const __bf16* Q = qr + (size_t)((b * NH + h) * T_SEQ) * 256;
  const __bf16* K = kr + (size_t)(b * T_SEQ) * 256;
  const __bf16* V = vt + (size_t)(b * 256) * T_SEQ;

  const int qbase = qi * 64;
  const int jt0 = (qi >= 8) ? 2 * qi - 16 : 0;
  const int jt1 = 2 * qi + 1;
  const int NT = jt1 - jt0 + 1;          // >= 2

  if (wave < 4) {
    // ------------------------------------------------------------- QK group
    const int kb = wave & 1, qh = wave >> 1;
    const int t = tid;                       // 0..255
    const int krow = t >> 5;                 // 0..7
    const int kcol = ((t & 31) ^ krow) * 8;

    bf16x8 qf[2][8];
#pragma unroll
    for (int qt = 0; qt < 2; ++qt)
#pragma unroll
      for (int c = 0; c < 8; ++c)
        qf[qt][c] = *(const bf16x8*)&Q[(size_t)(qbase + qh * 32 + qt * 16 + lrow) * 256 +
                                       c * 32 + quad * 8];

    // prologue: stage K(jt0), K(jt0+1); drain K(jt0) BEFORE the barrier.
#pragma unroll
    for (int i = 0; i < 4; ++i)
      gl2lds16(K + (size_t)(jt0 * 32 + i * 8 + krow) * 256 + kcol,
               &Ks[jt0 % 3][i * 2048 + t * 8]);
#pragma unroll
    for (int i = 0; i < 4; ++i)
      gl2lds16(K + (size_t)((jt0 + 1) * 32 + i * 8 + krow) * 256 + kcol,
               &Ks[(jt0 + 1) % 3][i * 2048 + t * 8]);
    asm volatile("s_waitcnt vmcnt(4)\n\ts_barrier" ::: "memory");

    for (int jt = jt0; jt <= jt1; ++jt) {
      // stage 2 ahead into the buffer whose readers retired 2 barriers ago
      if (jt + 2 <= jt1) {
#pragma unroll
        for (int i = 0; i < 4; ++i)
          gl2lds16(K + (size_t)((jt + 2) * 32 + i * 8 + krow) * 256 + kcol,
                   &Ks[(jt + 2) % 3][i * 2048 + t * 8]);
      }

      const __bf16* Kb = Ks[jt % 3];       // landed (drained pre-prev-barrier)
      floatx4 s[2] = {};
      __builtin_amdgcn_s_setprio(1);
#pragma unroll
      for (int c = 0; c < 8; ++c) {
        bf16x8 kf = *(const bf16x8*)&Kb[(kb * 16 + lrow) * 256 +
                                        ((c * 4 + quad) ^ l7) * 8];
        s[0] = mfma16(kf, qf[0][c], s[0]);
        s[1] = mfma16(kf, qf[1][c], s[1]);
      }
      __builtin_amdgcn_s_setprio(0);

      const bool full = (jt <= 2 * qi - 1) && (jt >= 2 * qi - 14);
      const float C1 = 0.09016844005556021f;   // log2(e)/16
      const float C2 = 23.083120654223415f;    // 16*log2(e)
      __bf16* Pb = Ps[jt & 1];
#pragma unroll
      for (int qt = 0; qt < 2; ++qt) {
        bf16x4 pk;
#pragma unroll
        for (int r = 0; r < 4; ++r) {
          float v = s[qt][r];
          if (!full) {
            const int jk = jt * 32 + kb * 16 + quad * 4 + r;
            const int iq = qbase + qh * 32 + qt * 16 + lrow;
            v = ((jk <= iq) && (jk + 512 >= iq)) ? v : -1e30f;
          }
          pk[r] = (__bf16)exp2f(v * C1 - C2);
        }
        const int q = qh * 32 + qt * 16 + lrow;
        const int chunk = (kb * 2 + (quad >> 1)) ^ ((q ^ (q >> 2)) & 3);
        *(bf16x4*)((char*)Pb + q * 64 + chunk * 16 + (quad & 1) * 8) = pk;
      }
      // drain P (lgkm) AND K(jt+1) (vmcnt) BEFORE the barrier; K(jt+2) flies.
      if (jt + 2 <= jt1)
        asm volatile("s_waitcnt lgkmcnt(0) vmcnt(4)\n\ts_barrier" ::: "memory");
      else
        asm volatile("s_waitcnt lgkmcnt(0) vmcnt(0)\n\ts_barrier" ::: "memory");
    }
  } else {
    // ------------------------------------------------------------- PV group
    const int dw = wave - 4;                 // d-64 slice
    const int t = tid - 256;                 // 0..255
    const int vrow4 = t >> 2;                // 0..63
    const int vcol = ((t & 3) ^ ((vrow4 ^ (vrow4 >> 2)) & 3)) * 8;

    bf16x8 onesv;
#pragma unroll
    for (int j = 0; j < 8; ++j) onesv[j] = (__bf16)1.0f;

    floatx4 o[4][4] = {};    // [qt][n]
    floatx4 lm[4] = {};

    // prologue: stage V(jt0); barrier matches QK's prologue barrier.
#pragma unroll
    for (int i = 0; i < 4; ++i)
      gl2lds16(V + (size_t)(i * 64 + vrow4) * T_SEQ + jt0 * 32 + vcol,
               &Vs[jt0 % 3][i * 2048 + t * 8]);
    asm volatile("s_barrier" ::: "memory");

    for (int ii = 0; ii <= NT; ++ii) {
      const int jv = jt0 + ii + 1;   // V tile to stage (1 ahead of this window)
      const int jp = jt0 + ii - 1;   // P/V tile to consume
      const bool stg = (jv <= jt1);  // block-uniform
      if (stg) {
#pragma unroll
        for (int i = 0; i < 4; ++i)
          gl2lds16(V + (size_t)(i * 64 + vrow4) * T_SEQ + jv * 32 + vcol,
                   &Vs[jv % 3][i * 2048 + t * 8]);
      }

      if (ii >= 1) {
        const __bf16* Pb = Ps[jp & 1];       // written pre-prev-barrier (lgkm)
        const __bf16* Vb = Vs[jp % 3];       // drained pre-prev-barrier (vmcnt)
        bf16x8 pf[4];
#pragma unroll
        for (int qt = 0; qt < 4; ++qt) {
          const int q = qt * 16 + lrow;
          pf[qt] = *(const bf16x8*)((char*)Pb + q * 64 +
                                    (quad ^ ((q ^ (q >> 2)) & 3)) * 16);
        }
        __builtin_amdgcn_s_setprio(1);
#pragma unroll
        for (int qt = 0; qt < 4; ++qt) lm[qt] = mfma16(pf[qt], onesv, lm[qt]);
#pragma unroll
        for (int n = 0; n < 4; ++n) {
          const int row = dw * 64 + n * 16 + lrow;
          bf16x8 vf = *(const bf16x8*)&Vb[row * 32 +
                                          ((quad ^ ((row ^ (row >> 2)) & 3)) * 8)];
#pragma unroll
          for (int qt = 0; qt < 4; ++qt)
            o[qt][n] = mfma16(pf[qt], vf, o[qt][n]);
        }
        __builtin_amdgcn_s_setprio(0);
      }

      if (ii < NT) {
        // drain V(jt0+ii) BEFORE the barrier; V(jv) stays in flight.
        if (stg)
          asm volatile("s_waitcnt vmcnt(4)\n\ts_barrier" ::: "memory");
        else
          asm volatile("s_waitcnt vmcnt(0)\n\ts_barrier" ::: "memory");
      }
    }

    // epilogue: O/l -> ao in (B,T,H*hd) layout
#pragma unroll
    for (int qt = 0; qt < 4; ++qt)
#pragma unroll
      for (int r = 0; r < 4; ++r) {
        const float rl = 1.0f / lm[qt][r];
        const int tg = qbase + qt * 16 + quad * 4 + r;
#pragma unroll
        for (int n = 0; n < 4; ++n)
          ao[((size_t)(b * T_SEQ + tg)) * CDIM + h * 256 + dw * 64 + n * 16 + lrow] =
              (__bf16)(o[qt][n][r] * rl);
      }
  }
}

// -----------------------------------------------------------------------------
extern "C" void kernel_launch(void* const* d_in, const int* in_sizes, int n_in,
                              void* d_out, int out_size, void* d_ws, size_t ws_size,
                              hipStream_t stream) {
  const float* x  = (const float*)d_in[0];
  const float* Wq = (const float*)d_in[1];
  const float* Wk = (const float*)d_in[2];
  const float* Wv = (const float*)d_in[3];
  const float* Wo = (const float*)d_in[4];
  const float* qg = (const float*)d_in[5];
  const float* kg = (const float*)d_in[6];
  float* out = (float*)d_out;

  const size_t M = (size_t)NB * T_SEQ;  // 8192
  char* ws = (char*)d_ws;
  __bf16* xb  = (__bf16*)ws; ws += M * CDIM * 2;
  __bf16* wb  = (__bf16*)ws; ws += (size_t)1536 * CDIM * 2;
  __bf16* wob = (__bf16*)ws; ws += (size_t)CDIM * CDIM * 2;
  __bf16* qkv = (__bf16*)ws; ws += M * 1536 * 2;
  __bf16* qr  = (__bf16*)ws; ws += M * CDIM * 2;
  __bf16* kr  = (__bf16*)ws; ws += M * HD * 2;
  __bf16* vt  = (__bf16*)ws; ws += M * HD * 2;
  __bf16* ao  = (__bf16*)ws;

  // all fp32->bf16 conversions in one launch
  cvt_all<<<10752, 256, 0, stream>>>(x, Wq, Wk, Wv, Wo, xb, wb, wob);

  // QKV projection: (8192 x 1536) = xb @ [Wq;Wk;Wv]^T  (proven 128^2 kernel)
  gemm_bt<__bf16><<<dim3(12, 64), 256, 0, stream>>>(xb, wb, qkv, 8192, 1536, 1024);

  // per-head RMSNorm + RoPE on Q,K; V transpose via LDS tiles
  rmsrope<<<5248, 256, 0, stream>>>(qkv, qg, kg, qr, kr, vt);

  // sliding-window flash attention: producer/consumer, race-free counted vmcnt
  attn<<<NB * NH * (T_SEQ / 64), 512, 0, stream>>>(qr, kr, vt, ao);

  // output projection to fp32 d_out  (proven 128^2 kernel)
  gemm_bt<float><<<dim3(8, 64), 256, 0, stream>>>(ao, wob, out, 8192, 1024, 1024);
}